// Round 19
// baseline (1002.169 us; speedup 1.0000x reference)
//
#include <hip/hip_runtime.h>

#define NB 256
#define NT 1000
#define ND 64
#define NH 128
#define TT 25            // t-tile for gi_pre (40 y-blocks)

typedef _Float16 h2 __attribute__((ext_vector_type(2)));

static __device__ __forceinline__ uint pk(float a, float b) {
    return __builtin_bit_cast(uint, __builtin_amdgcn_cvt_pkrtz(a, b));
}
static __device__ __forceinline__ float fdot2u(uint a, uint b, float c) {
#if __has_builtin(__builtin_amdgcn_fdot2)
    return __builtin_amdgcn_fdot2(__builtin_bit_cast(h2, a),
                                  __builtin_bit_cast(h2, b), c, false);
#else
    h2 ha = __builtin_bit_cast(h2, a), hb = __builtin_bit_cast(h2, b);
    return c + (float)ha.x * (float)hb.x + (float)ha.y * (float)hb.y;
#endif
}
static __device__ __forceinline__ float sigmoid_f(float x) {
    float e = __builtin_amdgcn_exp2f(-1.4426950408889634f * x);
    return __builtin_amdgcn_rcpf(1.0f + e);
}
static __device__ __forceinline__ float tanh_f(float x) {
    float e = __builtin_amdgcn_exp2f(-2.8853900817779268f * x);
    return 2.0f * __builtin_amdgcn_rcpf(1.0f + e) - 1.0f;
}
// quad butterfly sum via DPP
static __device__ __forceinline__ float qsum(float v) {
    int a = __builtin_amdgcn_update_dpp(0, __builtin_bit_cast(int, v),
                                        0xB1, 0xF, 0xF, true); // quad_perm(1,0,3,2)
    v += __builtin_bit_cast(float, a);
    int b = __builtin_amdgcn_update_dpp(0, __builtin_bit_cast(int, v),
                                        0x4E, 0xF, 0xF, true); // quad_perm(2,3,0,1)
    v += __builtin_bit_cast(float, b);
    return v;
}
// load 8 consecutive f32, pack to 4 f16x2 regs
static __device__ __forceinline__ void ld8(const float* p, uint* d) {
    const float4 A = *(const float4*)p;
    const float4 B = *(const float4*)(p + 4);
    d[0] = pk(A.x, A.y); d[1] = pk(A.z, A.w);
    d[2] = pk(B.x, B.y); d[3] = pk(B.z, B.w);
}
#define PIN(v) asm volatile("" : "+v"(v))
// raw barrier: orders LDS only; global prefetch loads stay in flight
#define WAVEBAR() asm volatile("s_waitcnt lgkmcnt(0)\n\ts_barrier" ::: "memory")

// ---------- gi precompute: giu[t][b][row] (f16) = W_ih@x + folded biases ----------
// EVERY entry is stored on every call (poison-once harness: all readable ws bytes
// must be rewritten deterministically — round-17 lesson). Compute is skipped for
// unmasked (t,b): those entries get 0 and are never consumed by the scan.
__global__ __launch_bounds__(384) void gi_pre(
    const float* __restrict__ x,      // (B,T,D)
    const float* __restrict__ W_ih,   // (384,64)
    const float* __restrict__ b_ih,   // (384)
    const float* __restrict__ b_hh,   // (384)
    const int*   __restrict__ mask,   // (B,T)
    ushort* __restrict__ giu)         // (T,B,384)
{
    __shared__ uint xt[TT][32];       // f16-packed x tile (3.2 KB)
    const int tid = threadIdx.x;      // W_ih row
    const int b   = blockIdx.x;
    const int t0  = blockIdx.y * TT;

    uint wr[32];
    const float* wrow = W_ih + (size_t)tid * ND;
#pragma unroll
    for (int k = 0; k < 8; ++k) ld8(wrow + k * 8, wr + k * 4);
    const float badd = (tid < 256) ? (b_ih[tid] + b_hh[tid]) : b_ih[tid];

    for (int i = tid; i < TT * 32; i += 384) {
        const int t = i >> 5, c = i & 31;
        const float2 v = *(const float2*)(x + ((size_t)b * NT + t0 + t) * ND + c * 2);
        xt[t][c] = pk(v.x, v.y);
    }
    __syncthreads();

    for (int t = 0; t < TT; ++t) {
        ushort val = 0;
        if (mask[(size_t)b * NT + t0 + t]) {       // block-uniform
            const uint4* xr = (const uint4*)&xt[t][0];   // broadcast reads
            float a0 = 0.0f, a1 = 0.0f;
#pragma unroll
            for (int k4 = 0; k4 < 8; ++k4) {
                const uint4 hv = xr[k4];
                a0 = fdot2u(wr[k4 * 4 + 0], hv.x, a0);
                a1 = fdot2u(wr[k4 * 4 + 1], hv.y, a1);
                a0 = fdot2u(wr[k4 * 4 + 2], hv.z, a0);
                a1 = fdot2u(wr[k4 * 4 + 3], hv.w, a1);
            }
            val = __builtin_bit_cast(ushort, (_Float16)(a0 + a1 + badd));
        }
        giu[((size_t)(t0 + t) * NB + b) * 384 + tid] = val;   // store ALWAYS
    }
}

// ---------- 3-phase scan (m==1) / 2-phase (m==0); 80-u32 fragment set ----------
template<int GI>
__global__
__attribute__((amdgpu_flat_work_group_size(512, 512)))
__attribute__((amdgpu_waves_per_eu(2, 2)))
void gruode_scan(
    const float* __restrict__ x,      // (B,T,D)  (GI=0 only)
    const float* __restrict__ tps,    // (T)
    const int*   __restrict__ mask,   // (B,T)
    const float* __restrict__ W_ih,   // (384,64)  (GI=0 only)
    const float* __restrict__ W_hh,   // (384,128)
    const float* __restrict__ b_ih,   // (384)
    const float* __restrict__ b_hh,   // (384)
    const float* __restrict__ nW1,    // (128,128)
    const float* __restrict__ nb1,    // (128)
    const float* __restrict__ nW2,    // (128,128)
    const float* __restrict__ nb2,    // (128)
    const float* __restrict__ W_out,  // (128,128)
    const float* __restrict__ b_out,  // (128)
    const ushort* __restrict__ giu,   // (T,B,384) f16, biases folded (GI=1)
    float* __restrict__ out)          // (B,128)
{
    __shared__ __align__(16) _Float16 sh_h[2][NH];
    __shared__ __align__(16) _Float16 sh_tmp[NH];
    __shared__ __align__(16) _Float16 sh_ode[NH];
    __shared__ float sh_eo[NH];
    __shared__ float sh_dt[NT];
    __shared__ int   sh_m[NT];

    const int tid = threadIdx.x;
    const int j   = tid >> 2;   // output row 0..127
    const int q   = tid & 3;    // K-quarter
    const int b   = blockIdx.x;
    const int kb  = q * 32;     // f16 col base
    const int qb  = q * 64;     // byte base within 128-f16 row

#define WSEL(i) (((i) + (q >> 1)) & 3)   // verified conflict-free rotation

    // ---- stage weights: 5 fragment sets = 80 u32 (fits 128-reg budget) ----
    uint w1[4][4], w2[4][4], whr[4][4], whz[4][4], whn[4][4];
#pragma unroll
    for (int i = 0; i < 4; ++i) {
        const int c = kb + (WSEL(i) << 3);
        ld8(nW1  + (size_t)(j      ) * NH + c, w1[i]);
        ld8(nW2  + (size_t)(j      ) * NH + c, w2[i]);
        ld8(W_hh + (size_t)(j      ) * NH + c, whr[i]);
        ld8(W_hh + (size_t)(j + 128) * NH + c, whz[i]);
        ld8(W_hh + (size_t)(j + 256) * NH + c, whn[i]);
    }
    uint wir[8], wiz[8], win[8];
    if constexpr (!GI) {
        const int kbi = q * 16;
        ld8(W_ih + (size_t)(j      ) * ND + kbi,     wir);
        ld8(W_ih + (size_t)(j      ) * ND + kbi + 8, wir + 4);
        ld8(W_ih + (size_t)(j + 128) * ND + kbi,     wiz);
        ld8(W_ih + (size_t)(j + 128) * ND + kbi + 8, wiz + 4);
        ld8(W_ih + (size_t)(j + 256) * ND + kbi,     win);
        ld8(W_ih + (size_t)(j + 256) * ND + kbi + 8, win + 4);
    }
    float bb1   = nb1[j];
    float bb2   = nb2[j];
    float brz_r = b_ih[j]       + b_hh[j];        // GI=0 path only
    float brz_z = b_ih[j + 128] + b_hh[j + 128];  // GI=0 path only
    float bin_n = b_ih[j + 256];                  // GI=0 path only
    float bhn_n = b_hh[j + 256];

#pragma unroll
    for (int i = 0; i < 4; ++i)
#pragma unroll
        for (int k = 0; k < 4; ++k) {
            PIN(w1[i][k]); PIN(w2[i][k]);
            PIN(whr[i][k]); PIN(whz[i][k]); PIN(whn[i][k]);
        }
    PIN(bb1); PIN(bb2); PIN(bhn_n);

    // ---- stage dt / mask; init h ----
    for (int s = tid; s < NT; s += 512) {
        sh_dt[s] = (s == 0) ? 0.0f : (tps[s] - tps[s - 1]);
        sh_m[s]  = mask[b * NT + s];
    }
    if (tid < NH) sh_h[0][tid] = (_Float16)0.0f;
    __syncthreads();

    float hj = 0.0f, hlast = 0.0f;
    int   seen = 0;

    // gi prefetch, 2 steps deep
    const size_t GSTR = (size_t)NB * 384;
    const ushort* gb = giu + (size_t)b * 384 + j;
    ushort c_r, c_z, c_n, n_r, n_z, n_n;
    const float* xbase = x + (size_t)b * NT * ND + q * 16;
    float4 xc0, xc1, xc2, xc3;
    if constexpr (GI) {
        c_r = gb[0];           c_z = gb[128];           c_n = gb[256];
        n_r = gb[GSTR];        n_z = gb[GSTR + 128];    n_n = gb[GSTR + 256];
    } else {
        xc0 = *(const float4*)(xbase);
        xc1 = *(const float4*)(xbase + 4);
        xc2 = *(const float4*)(xbase + 8);
        xc3 = *(const float4*)(xbase + 12);
    }
    float dtc = sh_dt[0];
    int   mc  = sh_m[0];

    for (int s = 0; s < NT; ++s) {
        const int cur = s & 1, nxt = cur ^ 1;

        // issue prefetches (stay in flight across raw barriers)
        ushort p_r, p_z, p_n;
        float4 xn0, xn1, xn2, xn3;
        if constexpr (GI) {
            const int sp = (s + 2 < NT) ? (s + 2) : (NT - 1);
            const ushort* g2 = gb + (size_t)sp * GSTR;
            p_r = g2[0]; p_z = g2[128]; p_n = g2[256];
        } else {
            const int sn_ = (s + 1 < NT) ? (s + 1) : s;
            const float* xr = xbase + (size_t)sn_ * ND;
            xn0 = *(const float4*)(xr);
            xn1 = *(const float4*)(xr + 4);
            xn2 = *(const float4*)(xr + 8);
            xn3 = *(const float4*)(xr + 12);
        }
        const int sn = (s + 1 < NT) ? (s + 1) : s;
        const float dt_n = sh_dt[sn];
        const int   m_n  = sh_m[sn];

        const int   m   = mc;                  // uniform per block
        const float dte = seen ? dtc : 0.0f;   // r_fill freeze

        // input-gate contributions (biases folded in giu for GI=1)
        float grf, gzf, gnf;
        if constexpr (GI) {
            grf = (float)__builtin_bit_cast(_Float16, c_r);
            gzf = (float)__builtin_bit_cast(_Float16, c_z);
            gnf = (float)__builtin_bit_cast(_Float16, c_n);
        } else {
            uint xh[8];
            xh[0] = pk(xc0.x, xc0.y); xh[1] = pk(xc0.z, xc0.w);
            xh[2] = pk(xc1.x, xc1.y); xh[3] = pk(xc1.z, xc1.w);
            xh[4] = pk(xc2.x, xc2.y); xh[5] = pk(xc2.z, xc2.w);
            xh[6] = pk(xc3.x, xc3.y); xh[7] = pk(xc3.z, xc3.w);
            grf = gzf = gnf = 0.0f;
            if (m) {
#pragma unroll
                for (int k = 0; k < 8; ++k) {
                    grf = fdot2u(wir[k], xh[k], grf);
                    gzf = fdot2u(wiz[k], xh[k], gzf);
                    gnf = fdot2u(win[k], xh[k], gnf);
                }
            }
        }

        // ---- phase A: a1 = W1 h (2 ILP chains) ----
        float a1a = 0.0f, a1b = 0.0f;
        const char* hb = (const char*)&sh_h[cur][0];
#pragma unroll
        for (int i = 0; i < 4; ++i) {
            const uint4 hv = *(const uint4*)(hb + qb + WSEL(i) * 16);
            a1a = fdot2u(w1[i][0], hv.x, a1a); a1b = fdot2u(w1[i][1], hv.y, a1b);
            a1a = fdot2u(w1[i][2], hv.z, a1a); a1b = fdot2u(w1[i][3], hv.w, a1b);
        }
        const float a1q = qsum(a1a + a1b);
        if (q == 0) sh_tmp[j] = (_Float16)tanh_f(a1q + bb1);
        WAVEBAR();

        // ---- phase B: a2 = W2 tmp -> h_ode (2 ILP chains) ----
        float a2a = 0.0f, a2b = 0.0f;
#pragma unroll
        for (int i = 0; i < 4; ++i) {
            const uint4 tv = *(const uint4*)((const char*)sh_tmp + qb + WSEL(i) * 16);
            a2a = fdot2u(w2[i][0], tv.x, a2a); a2b = fdot2u(w2[i][1], tv.y, a2b);
            a2a = fdot2u(w2[i][2], tv.z, a2a); a2b = fdot2u(w2[i][3], tv.w, a2b);
        }
        const float a2q  = qsum(a2a + a2b);
        const float hode = hj + dte * (a2q + bb2);

        float hnew;
        if (m) {
            // ---- phase C: AH = W_hh h_ode ; gates (m==1 only, block-uniform) ----
            if (q == 0) sh_ode[j] = (_Float16)hode;
            WAVEBAR();
            float ahr = 0.0f, ahz = 0.0f, ahn = 0.0f;
#pragma unroll
            for (int i = 0; i < 4; ++i) {
                const uint4 hv = *(const uint4*)((const char*)sh_ode + qb + WSEL(i) * 16);
                ahr = fdot2u(whr[i][0], hv.x, ahr); ahr = fdot2u(whr[i][1], hv.y, ahr);
                ahr = fdot2u(whr[i][2], hv.z, ahr); ahr = fdot2u(whr[i][3], hv.w, ahr);
                ahz = fdot2u(whz[i][0], hv.x, ahz); ahz = fdot2u(whz[i][1], hv.y, ahz);
                ahz = fdot2u(whz[i][2], hv.z, ahz); ahz = fdot2u(whz[i][3], hv.w, ahz);
                ahn = fdot2u(whn[i][0], hv.x, ahn); ahn = fdot2u(whn[i][1], hv.y, ahn);
                ahn = fdot2u(whn[i][2], hv.z, ahn); ahn = fdot2u(whn[i][3], hv.w, ahn);
            }
            const float sr_t = qsum(ahr);
            const float sz_t = qsum(ahz);
            const float hn_t = qsum(ahn);
            float r, z, n;
            if constexpr (GI) {
                r = sigmoid_f(sr_t + grf);
                z = sigmoid_f(sz_t + gzf);
                n = tanh_f(gnf + r * (hn_t + bhn_n));
            } else {
                r = sigmoid_f(sr_t + grf + brz_r);
                z = sigmoid_f(sz_t + gzf + brz_z);
                n = tanh_f(gnf + bin_n + r * (hn_t + bhn_n));
            }
            hnew  = (1.0f - z) * n + z * hode;
            hlast = hnew;
        } else {
            hnew = hode;
        }

        if (q == 0) sh_h[nxt][j] = (_Float16)hnew;
        hj = hnew;
        seen |= m;
        if constexpr (GI) { c_r = n_r; c_z = n_z; c_n = n_n; n_r = p_r; n_z = p_z; n_n = p_n; }
        else { xc0 = xn0; xc1 = xn1; xc2 = xn2; xc3 = xn3; }
        dtc = dt_n; mc = m_n;
        WAVEBAR();
    }

    // ---- epilogue (f32): out = W_out @ h_last + b_out ----
    if (q == 0) sh_eo[j] = hlast;
    __syncthreads();
    float ao = 0.0f;
#pragma unroll
    for (int i = 0; i < 8; ++i) {
        const int c = kb + (((i + 2 * q) & 7) << 2);
        const float4 wv = *(const float4*)(W_out + (size_t)j * NH + c);
        const float4 hv = *(const float4*)(sh_eo + c);
        ao += wv.x * hv.x + wv.y * hv.y + wv.z * hv.z + wv.w * hv.w;
    }
    ao = qsum(ao);
    if (q == 0) out[(size_t)b * NH + j] = ao + b_out[j];
}

extern "C" void kernel_launch(void* const* d_in, const int* in_sizes, int n_in,
                              void* d_out, int out_size, void* d_ws, size_t ws_size,
                              hipStream_t stream) {
    const float* x     = (const float*)d_in[0];
    const float* tps   = (const float*)d_in[1];
    const int*   mask  = (const int*)  d_in[2];
    const float* W_ih  = (const float*)d_in[3];
    const float* W_hh  = (const float*)d_in[4];
    const float* b_ih  = (const float*)d_in[5];
    const float* b_hh  = (const float*)d_in[6];
    const float* nW1   = (const float*)d_in[7];
    const float* nb1   = (const float*)d_in[8];
    const float* nW2   = (const float*)d_in[9];
    const float* nb2   = (const float*)d_in[10];
    const float* W_out = (const float*)d_in[11];
    const float* b_out = (const float*)d_in[12];
    float* out = (float*)d_out;

    const size_t GI_BYTES = (size_t)NT * NB * 384 * sizeof(ushort);    // 196,608,000
    ushort* giu = (ushort*)d_ws;

    if (ws_size >= GI_BYTES) {
        gi_pre<<<dim3(NB, NT / TT), dim3(384), 0, stream>>>(x, W_ih, b_ih, b_hh, mask, giu);
        gruode_scan<1><<<dim3(NB), dim3(512), 0, stream>>>(
            x, tps, mask, W_ih, W_hh, b_ih, b_hh,
            nW1, nb1, nW2, nb2, W_out, b_out, giu, out);
    } else {
        gruode_scan<0><<<dim3(NB), dim3(512), 0, stream>>>(
            x, tps, mask, W_ih, W_hh, b_ih, b_hh,
            nW1, nb1, nW2, nb2, W_out, b_out, nullptr, out);
    }
}

// Round 20
// 899.122 us; speedup vs baseline: 1.1146x; 1.1146x over previous
//
#include <hip/hip_runtime.h>

#define NB 256
#define NT 1000
#define ND 64
#define NH 128

typedef _Float16 h2 __attribute__((ext_vector_type(2)));
typedef _Float16 f16x8 __attribute__((ext_vector_type(8)));
typedef float    f32x4 __attribute__((ext_vector_type(4)));
typedef uint     u32x4 __attribute__((ext_vector_type(4)));

static __device__ __forceinline__ uint pk(float a, float b) {
    return __builtin_bit_cast(uint, __builtin_amdgcn_cvt_pkrtz(a, b));
}
static __device__ __forceinline__ float fdot2u(uint a, uint b, float c) {
#if __has_builtin(__builtin_amdgcn_fdot2)
    return __builtin_amdgcn_fdot2(__builtin_bit_cast(h2, a),
                                  __builtin_bit_cast(h2, b), c, false);
#else
    h2 ha = __builtin_bit_cast(h2, a), hb = __builtin_bit_cast(h2, b);
    return c + (float)ha.x * (float)hb.x + (float)ha.y * (float)hb.y;
#endif
}
static __device__ __forceinline__ float sigmoid_f(float x) {
    float e = __builtin_amdgcn_exp2f(-1.4426950408889634f * x);
    return __builtin_amdgcn_rcpf(1.0f + e);
}
static __device__ __forceinline__ float tanh_f(float x) {
    float e = __builtin_amdgcn_exp2f(-2.8853900817779268f * x);
    return 2.0f * __builtin_amdgcn_rcpf(1.0f + e) - 1.0f;
}
// quad butterfly sum via DPP
static __device__ __forceinline__ float qsum(float v) {
    int a = __builtin_amdgcn_update_dpp(0, __builtin_bit_cast(int, v),
                                        0xB1, 0xF, 0xF, true); // quad_perm(1,0,3,2)
    v += __builtin_bit_cast(float, a);
    int b = __builtin_amdgcn_update_dpp(0, __builtin_bit_cast(int, v),
                                        0x4E, 0xF, 0xF, true); // quad_perm(2,3,0,1)
    v += __builtin_bit_cast(float, b);
    return v;
}
// load 8 consecutive f32, pack to 4 f16x2 regs
static __device__ __forceinline__ void ld8(const float* p, uint* d) {
    const float4 A = *(const float4*)p;
    const float4 B = *(const float4*)(p + 4);
    d[0] = pk(A.x, A.y); d[1] = pk(A.z, A.w);
    d[2] = pk(B.x, B.y); d[3] = pk(B.z, B.w);
}
// load 8 consecutive f32 as one MFMA A/B-fragment (layout verified r6/r11)
static __device__ __forceinline__ f16x8 ldWfrag(const float* p) {
    const float4 a = *(const float4*)p;
    const float4 b = *(const float4*)(p + 4);
    u32x4 u = { pk(a.x, a.y), pk(a.z, a.w), pk(b.x, b.y), pk(b.z, b.w) };
    return __builtin_bit_cast(f16x8, u);
}
#define PIN(v) asm volatile("" : "+v"(v))
#define MFMA(a, b, c) __builtin_amdgcn_mfma_f32_16x16x32_f16((a), (b), (c), 0, 0, 0)
// raw barrier: orders LDS only; global prefetch loads stay in flight
#define WAVEBAR() asm volatile("s_waitcnt lgkmcnt(0)\n\ts_barrier" ::: "memory")

// ---------- gi precompute via MFMA: giu[t][b][row] (f16) = W_ih@x + biases ----------
// GEMM (384x64)@(64 x 16t-tile). Cols = t-samples. Loads clamp t; stores guard
// t<NT, so every readable (t,b) entry is rewritten each call (write-all rule).
__global__ __launch_bounds__(512) void gi_pre_mfma(
    const float* __restrict__ x,      // (B,T,D)
    const float* __restrict__ W_ih,   // (384,64)
    const float* __restrict__ b_ih,   // (384)
    const float* __restrict__ b_hh,   // (384)
    ushort* __restrict__ giu)         // (T,B,384)
{
    const int tid   = threadIdx.x;
    const int w     = tid >> 6;       // wave 0..7
    const int lane  = tid & 63;
    const int n     = lane & 15;      // D col = t within tile
    const int kg    = lane >> 4;      // D rows kg*4+rr
    const int b     = blockIdx.x;
    const int tbase = blockIdx.y * 128;

    // A-fragments: wave w owns row-tiles {w, w+8, w+16} (rows rt*16..+15)
    f16x8  aF[3][2];
    float4 badd[3];
#pragma unroll
    for (int g = 0; g < 3; ++g) {
        const int row0 = (w + 8 * g) * 16;
#pragma unroll
        for (int ks = 0; ks < 2; ++ks)
            aF[g][ks] = ldWfrag(W_ih + (size_t)(row0 + n) * ND + ks * 32 + kg * 8);
        const int jb = row0 + kg * 4;
        float4 bi = *(const float4*)(b_ih + jb);
        if (g < 2) {   // rows <256: r/z gates get b_ih+b_hh; n gate b_ih only
            const float4 bh = *(const float4*)(b_hh + jb);
            bi.x += bh.x; bi.y += bh.y; bi.z += bh.z; bi.w += bh.w;
        }
        badd[g] = bi;
    }

    const f32x4 z4 = {0, 0, 0, 0};
    for (int tt = 0; tt < 8; ++tt) {
        const int t  = tbase + tt * 16 + n;
        const int tc = (t < NT) ? t : (NT - 1);        // clamp loads only
        const float* xr = x + ((size_t)b * NT + tc) * ND + kg * 8;
        const f16x8 bF0 = ldWfrag(xr);        // k = kg*8 .. +8
        const f16x8 bF1 = ldWfrag(xr + 32);   // k = 32+kg*8 .. +8
#pragma unroll
        for (int g = 0; g < 3; ++g) {
            f32x4 D = MFMA(aF[g][0], bF0, z4);
            D = MFMA(aF[g][1], bF1, D);
            if (t < NT) {
                const int jb = (w + 8 * g) * 16 + kg * 4;
                *(uint2*)(giu + ((size_t)t * NB + b) * 384 + jb) =
                    make_uint2(pk(D[0] + badd[g].x, D[1] + badd[g].y),
                               pk(D[2] + badd[g].z, D[3] + badd[g].w));
            }
        }
    }
}

// ---------- 3-phase scan (m==1) / 2-phase (m==0); 80-u32 fragment set ----------
template<int GI>
__global__
__attribute__((amdgpu_flat_work_group_size(512, 512)))
__attribute__((amdgpu_waves_per_eu(2, 2)))
void gruode_scan(
    const float* __restrict__ x,      // (B,T,D)  (GI=0 only)
    const float* __restrict__ tps,    // (T)
    const int*   __restrict__ mask,   // (B,T)
    const float* __restrict__ W_ih,   // (384,64)  (GI=0 only)
    const float* __restrict__ W_hh,   // (384,128)
    const float* __restrict__ b_ih,   // (384)
    const float* __restrict__ b_hh,   // (384)
    const float* __restrict__ nW1,    // (128,128)
    const float* __restrict__ nb1,    // (128)
    const float* __restrict__ nW2,    // (128,128)
    const float* __restrict__ nb2,    // (128)
    const float* __restrict__ W_out,  // (128,128)
    const float* __restrict__ b_out,  // (128)
    const ushort* __restrict__ giu,   // (T,B,384) f16, biases folded (GI=1)
    float* __restrict__ out)          // (B,128)
{
    __shared__ __align__(16) _Float16 sh_h[2][NH];
    __shared__ __align__(16) _Float16 sh_tmp[NH];
    __shared__ __align__(16) _Float16 sh_ode[NH];
    __shared__ float sh_eo[NH];
    __shared__ float sh_dt[NT];
    __shared__ int   sh_m[NT];

    const int tid = threadIdx.x;
    const int j   = tid >> 2;   // output row 0..127
    const int q   = tid & 3;    // K-quarter
    const int b   = blockIdx.x;
    const int kb  = q * 32;     // f16 col base
    const int qb  = q * 64;     // byte base within 128-f16 row

#define WSEL(i) (((i) + (q >> 1)) & 3)   // verified conflict-free rotation

    // ---- stage weights: 5 fragment sets = 80 u32 (fits 128-reg budget) ----
    uint w1[4][4], w2[4][4], whr[4][4], whz[4][4], whn[4][4];
#pragma unroll
    for (int i = 0; i < 4; ++i) {
        const int c = kb + (WSEL(i) << 3);
        ld8(nW1  + (size_t)(j      ) * NH + c, w1[i]);
        ld8(nW2  + (size_t)(j      ) * NH + c, w2[i]);
        ld8(W_hh + (size_t)(j      ) * NH + c, whr[i]);
        ld8(W_hh + (size_t)(j + 128) * NH + c, whz[i]);
        ld8(W_hh + (size_t)(j + 256) * NH + c, whn[i]);
    }
    uint wir[8], wiz[8], win[8];
    if constexpr (!GI) {
        const int kbi = q * 16;
        ld8(W_ih + (size_t)(j      ) * ND + kbi,     wir);
        ld8(W_ih + (size_t)(j      ) * ND + kbi + 8, wir + 4);
        ld8(W_ih + (size_t)(j + 128) * ND + kbi,     wiz);
        ld8(W_ih + (size_t)(j + 128) * ND + kbi + 8, wiz + 4);
        ld8(W_ih + (size_t)(j + 256) * ND + kbi,     win);
        ld8(W_ih + (size_t)(j + 256) * ND + kbi + 8, win + 4);
    }
    float bb1   = nb1[j];
    float bb2   = nb2[j];
    float brz_r = b_ih[j]       + b_hh[j];        // GI=0 path only
    float brz_z = b_ih[j + 128] + b_hh[j + 128];  // GI=0 path only
    float bin_n = b_ih[j + 256];                  // GI=0 path only
    float bhn_n = b_hh[j + 256];

#pragma unroll
    for (int i = 0; i < 4; ++i)
#pragma unroll
        for (int k = 0; k < 4; ++k) {
            PIN(w1[i][k]); PIN(w2[i][k]);
            PIN(whr[i][k]); PIN(whz[i][k]); PIN(whn[i][k]);
        }
    PIN(bb1); PIN(bb2); PIN(bhn_n);

    // ---- stage dt / mask; init h ----
    for (int s = tid; s < NT; s += 512) {
        sh_dt[s] = (s == 0) ? 0.0f : (tps[s] - tps[s - 1]);
        sh_m[s]  = mask[b * NT + s];
    }
    if (tid < NH) sh_h[0][tid] = (_Float16)0.0f;
    __syncthreads();

    float hj = 0.0f, hlast = 0.0f;
    int   seen = 0;

    // gi prefetch, 2 steps deep
    const size_t GSTR = (size_t)NB * 384;
    const ushort* gb = giu + (size_t)b * 384 + j;
    ushort c_r, c_z, c_n, n_r, n_z, n_n;
    const float* xbase = x + (size_t)b * NT * ND + q * 16;
    float4 xc0, xc1, xc2, xc3;
    if constexpr (GI) {
        c_r = gb[0];           c_z = gb[128];           c_n = gb[256];
        n_r = gb[GSTR];        n_z = gb[GSTR + 128];    n_n = gb[GSTR + 256];
    } else {
        xc0 = *(const float4*)(xbase);
        xc1 = *(const float4*)(xbase + 4);
        xc2 = *(const float4*)(xbase + 8);
        xc3 = *(const float4*)(xbase + 12);
    }
    float dtc = sh_dt[0];
    int   mc  = sh_m[0];

    for (int s = 0; s < NT; ++s) {
        const int cur = s & 1, nxt = cur ^ 1;

        // issue prefetches (stay in flight across raw barriers)
        ushort p_r, p_z, p_n;
        float4 xn0, xn1, xn2, xn3;
        if constexpr (GI) {
            const int sp = (s + 2 < NT) ? (s + 2) : (NT - 1);
            const ushort* g2 = gb + (size_t)sp * GSTR;
            p_r = g2[0]; p_z = g2[128]; p_n = g2[256];
        } else {
            const int sn_ = (s + 1 < NT) ? (s + 1) : s;
            const float* xr = xbase + (size_t)sn_ * ND;
            xn0 = *(const float4*)(xr);
            xn1 = *(const float4*)(xr + 4);
            xn2 = *(const float4*)(xr + 8);
            xn3 = *(const float4*)(xr + 12);
        }
        const int sn = (s + 1 < NT) ? (s + 1) : s;
        const float dt_n = sh_dt[sn];
        const int   m_n  = sh_m[sn];

        const int   m   = mc;                  // uniform per block
        const float dte = seen ? dtc : 0.0f;   // r_fill freeze

        // input-gate contributions (biases folded in giu for GI=1)
        float grf, gzf, gnf;
        if constexpr (GI) {
            grf = (float)__builtin_bit_cast(_Float16, c_r);
            gzf = (float)__builtin_bit_cast(_Float16, c_z);
            gnf = (float)__builtin_bit_cast(_Float16, c_n);
        } else {
            uint xh[8];
            xh[0] = pk(xc0.x, xc0.y); xh[1] = pk(xc0.z, xc0.w);
            xh[2] = pk(xc1.x, xc1.y); xh[3] = pk(xc1.z, xc1.w);
            xh[4] = pk(xc2.x, xc2.y); xh[5] = pk(xc2.z, xc2.w);
            xh[6] = pk(xc3.x, xc3.y); xh[7] = pk(xc3.z, xc3.w);
            grf = gzf = gnf = 0.0f;
            if (m) {
#pragma unroll
                for (int k = 0; k < 8; ++k) {
                    grf = fdot2u(wir[k], xh[k], grf);
                    gzf = fdot2u(wiz[k], xh[k], gzf);
                    gnf = fdot2u(win[k], xh[k], gnf);
                }
            }
        }

        // ---- phase A: a1 = W1 h (2 ILP chains) ----
        float a1a = 0.0f, a1b = 0.0f;
        const char* hb = (const char*)&sh_h[cur][0];
#pragma unroll
        for (int i = 0; i < 4; ++i) {
            const uint4 hv = *(const uint4*)(hb + qb + WSEL(i) * 16);
            a1a = fdot2u(w1[i][0], hv.x, a1a); a1b = fdot2u(w1[i][1], hv.y, a1b);
            a1a = fdot2u(w1[i][2], hv.z, a1a); a1b = fdot2u(w1[i][3], hv.w, a1b);
        }
        const float a1q = qsum(a1a + a1b);
        if (q == 0) sh_tmp[j] = (_Float16)tanh_f(a1q + bb1);
        WAVEBAR();

        // ---- phase B: a2 = W2 tmp -> h_ode (2 ILP chains) ----
        float a2a = 0.0f, a2b = 0.0f;
#pragma unroll
        for (int i = 0; i < 4; ++i) {
            const uint4 tv = *(const uint4*)((const char*)sh_tmp + qb + WSEL(i) * 16);
            a2a = fdot2u(w2[i][0], tv.x, a2a); a2b = fdot2u(w2[i][1], tv.y, a2b);
            a2a = fdot2u(w2[i][2], tv.z, a2a); a2b = fdot2u(w2[i][3], tv.w, a2b);
        }
        const float a2q  = qsum(a2a + a2b);
        const float hode = hj + dte * (a2q + bb2);

        float hnew;
        if (m) {
            // ---- phase C: AH = W_hh h_ode ; gates (m==1 only, block-uniform) ----
            if (q == 0) sh_ode[j] = (_Float16)hode;
            WAVEBAR();
            float ahr = 0.0f, ahz = 0.0f, ahn = 0.0f;
#pragma unroll
            for (int i = 0; i < 4; ++i) {
                const uint4 hv = *(const uint4*)((const char*)sh_ode + qb + WSEL(i) * 16);
                ahr = fdot2u(whr[i][0], hv.x, ahr); ahr = fdot2u(whr[i][1], hv.y, ahr);
                ahr = fdot2u(whr[i][2], hv.z, ahr); ahr = fdot2u(whr[i][3], hv.w, ahr);
                ahz = fdot2u(whz[i][0], hv.x, ahz); ahz = fdot2u(whz[i][1], hv.y, ahz);
                ahz = fdot2u(whz[i][2], hv.z, ahz); ahz = fdot2u(whz[i][3], hv.w, ahz);
                ahn = fdot2u(whn[i][0], hv.x, ahn); ahn = fdot2u(whn[i][1], hv.y, ahn);
                ahn = fdot2u(whn[i][2], hv.z, ahn); ahn = fdot2u(whn[i][3], hv.w, ahn);
            }
            const float sr_t = qsum(ahr);
            const float sz_t = qsum(ahz);
            const float hn_t = qsum(ahn);
            float r, z, n;
            if constexpr (GI) {
                r = sigmoid_f(sr_t + grf);
                z = sigmoid_f(sz_t + gzf);
                n = tanh_f(gnf + r * (hn_t + bhn_n));
            } else {
                r = sigmoid_f(sr_t + grf + brz_r);
                z = sigmoid_f(sz_t + gzf + brz_z);
                n = tanh_f(gnf + bin_n + r * (hn_t + bhn_n));
            }
            hnew  = (1.0f - z) * n + z * hode;
            hlast = hnew;
        } else {
            hnew = hode;
        }

        if (q == 0) sh_h[nxt][j] = (_Float16)hnew;
        hj = hnew;
        seen |= m;
        if constexpr (GI) { c_r = n_r; c_z = n_z; c_n = n_n; n_r = p_r; n_z = p_z; n_n = p_n; }
        else { xc0 = xn0; xc1 = xn1; xc2 = xn2; xc3 = xn3; }
        dtc = dt_n; mc = m_n;
        WAVEBAR();
    }

    // ---- epilogue (f32): out = W_out @ h_last + b_out ----
    if (q == 0) sh_eo[j] = hlast;
    __syncthreads();
    float ao = 0.0f;
#pragma unroll
    for (int i = 0; i < 8; ++i) {
        const int c = kb + (((i + 2 * q) & 7) << 2);
        const float4 wv = *(const float4*)(W_out + (size_t)j * NH + c);
        const float4 hv = *(const float4*)(sh_eo + c);
        ao += wv.x * hv.x + wv.y * hv.y + wv.z * hv.z + wv.w * hv.w;
    }
    ao = qsum(ao);
    if (q == 0) out[(size_t)b * NH + j] = ao + b_out[j];
}

extern "C" void kernel_launch(void* const* d_in, const int* in_sizes, int n_in,
                              void* d_out, int out_size, void* d_ws, size_t ws_size,
                              hipStream_t stream) {
    const float* x     = (const float*)d_in[0];
    const float* tps   = (const float*)d_in[1];
    const int*   mask  = (const int*)  d_in[2];
    const float* W_ih  = (const float*)d_in[3];
    const float* W_hh  = (const float*)d_in[4];
    const float* b_ih  = (const float*)d_in[5];
    const float* b_hh  = (const float*)d_in[6];
    const float* nW1   = (const float*)d_in[7];
    const float* nb1   = (const float*)d_in[8];
    const float* nW2   = (const float*)d_in[9];
    const float* nb2   = (const float*)d_in[10];
    const float* W_out = (const float*)d_in[11];
    const float* b_out = (const float*)d_in[12];
    float* out = (float*)d_out;

    const size_t GI_BYTES = (size_t)NT * NB * 384 * sizeof(ushort);    // 196,608,000
    ushort* giu = (ushort*)d_ws;

    if (ws_size >= GI_BYTES) {
        gi_pre_mfma<<<dim3(NB, 8), dim3(512), 0, stream>>>(x, W_ih, b_ih, b_hh, giu);
        gruode_scan<1><<<dim3(NB), dim3(512), 0, stream>>>(
            x, tps, mask, W_ih, W_hh, b_ih, b_hh,
            nW1, nb1, nW2, nb2, W_out, b_out, giu, out);
    } else {
        gruode_scan<0><<<dim3(NB), dim3(512), 0, stream>>>(
            x, tps, mask, W_ih, W_hh, b_ih, b_hh,
            nW1, nb1, nW2, nb2, W_out, b_out, nullptr, out);
    }
}